// Round 6
// baseline (461.061 us; speedup 1.0000x reference)
//
#include <hip/hip_runtime.h>

#define DIM 64

__device__ __forceinline__ float bf2f(unsigned short u) {
    union { unsigned int i; float f; } v; v.i = ((unsigned int)u) << 16; return v.f;
}
__device__ __forceinline__ unsigned short f2bf(float f) {
    union { float f; unsigned int i; } v; v.f = f;
    unsigned int r = v.i + 0x7fff + ((v.i >> 16) & 1);   // RNE (no NaN inputs here)
    return (unsigned short)(r >> 16);
}
__device__ __forceinline__ float4 u2f4(ushort4 u) {
    float4 f; f.x = bf2f(u.x); f.y = bf2f(u.y); f.z = bf2f(u.z); f.w = bf2f(u.w);
    return f;
}
__device__ __forceinline__ ushort4 f2u4(float4 f) {
    ushort4 u; u.x = f2bf(f.x); u.y = f2bf(f.y); u.z = f2bf(f.z); u.w = f2bf(f.w);
    return u;
}
__device__ __forceinline__ float4 fma4(float4 a, float s, float4 c) {
    c.x = fmaf(a.x, s, c.x); c.y = fmaf(a.y, s, c.y);
    c.z = fmaf(a.z, s, c.z); c.w = fmaf(a.w, s, c.w);
    return c;
}

// ---- fused: degree count (first 3E threads) + emb fp32->bf16 convert ----
__global__ void deg_cvt_kernel(const int* __restrict__ d0, const int* __restrict__ d1,
                               const int* __restrict__ d2, int* __restrict__ degi,
                               const float4* __restrict__ e0, const float4* __restrict__ e1,
                               const float4* __restrict__ e2, ushort4* __restrict__ embh,
                               int NP, int NT, int NG, int E) {
    int i = blockIdx.x * blockDim.x + threadIdx.x;
    int degN = 3 * E;
    if (i < degN) {
        int g = i / E;
        int j = i - g * E;
        const int* dd = (g == 0) ? d0 : (g == 1) ? d1 : d2;
        int base = (g == 0) ? 0 : (g == 1) ? NP : NP + NT;
        atomicAdd(&degi[base + dd[j]], 1);
        return;
    }
    int i2 = i - degN;
    int np16 = NP * 16, nt16 = NT * 16, ng16 = NG * 16;
    if (i2 >= np16 + nt16 + ng16) return;
    const float4* s; int j;
    if (i2 < np16)              { s = e0; j = i2; }
    else if (i2 < np16 + nt16)  { s = e1; j = i2 - np16; }
    else                        { s = e2; j = i2 - np16 - nt16; }
    embh[i2] = f2u4(s[j]);
}

// ---- parallel scan, stage 1: per-block (256-elem) sums ----
__global__ void block_sums(const int* __restrict__ degi, int* __restrict__ bsum, int n) {
    int i = blockIdx.x * 256 + threadIdx.x;
    int v = (i < n) ? degi[i] : 0;
#pragma unroll
    for (int s = 1; s < 64; s <<= 1) v += __shfl_xor(v, s, 64);
    __shared__ int ws[4];
    if ((threadIdx.x & 63) == 0) ws[threadIdx.x >> 6] = v;
    __syncthreads();
    if (threadIdx.x == 0) bsum[blockIdx.x] = ws[0] + ws[1] + ws[2] + ws[3];
}

// ---- stage 2: exclusive scan of block sums (single block, nb <= 1024) ----
__global__ void scan_bsums(int* __restrict__ bsum, int nb) {
    int lane = threadIdx.x & 63, wid = threadIdx.x >> 6;
    int v = (threadIdx.x < nb) ? bsum[threadIdx.x] : 0;
    int x = v;
#pragma unroll
    for (int s = 1; s < 64; s <<= 1) {
        int y = __shfl_up(x, s, 64);
        if (lane >= s) x += y;
    }
    __shared__ int ws[16];
    if (lane == 63) ws[wid] = x;
    __syncthreads();
    int pre = 0;
    for (int w2 = 0; w2 < wid; ++w2) pre += ws[w2];
    if (threadIdx.x < nb) bsum[threadIdx.x] = pre + x - v;   // exclusive
}

// ---- stage 3: global exclusive offsets + cursor copy + dinv ----
__global__ void scatter_offs(const int* __restrict__ degi, const int* __restrict__ bpre,
                             int* __restrict__ offs, int* __restrict__ cur,
                             float* __restrict__ dinv, int n, int total) {
    int i = blockIdx.x * 256 + threadIdx.x;
    int lane = threadIdx.x & 63, wid = threadIdx.x >> 6;
    int v = (i < n) ? degi[i] : 0;
    int x = v;
#pragma unroll
    for (int s = 1; s < 64; s <<= 1) {
        int y = __shfl_up(x, s, 64);
        if (lane >= s) x += y;
    }
    __shared__ int ws[4];
    if (lane == 63) ws[wid] = x;
    __syncthreads();
    int pre = bpre[blockIdx.x];
    for (int w2 = 0; w2 < wid; ++w2) pre += ws[w2];
    if (i < n) {
        int e = pre + x - v;
        offs[i] = e; cur[i] = e;
        dinv[i] = (v > 0) ? rsqrtf((float)v) : 0.0f;
    }
    if (i == 0) offs[n] = total;
}

// ---- XCD-partitioned permute: cohort p (blockIdx%8) scatters only edges whose
//      CSR position falls in partition p -> each ei cache line written by 1 XCD ----
__global__ void permute_part(const int* __restrict__ up, const int* __restrict__ ut,
                             const int* __restrict__ ug, const int* __restrict__ offs,
                             int* __restrict__ cur, int* __restrict__ ei,
                             int NP, int NT, int E) {
    const int p = blockIdx.x & 7;            // partition / XCD cohort
    const int c = blockIdx.x >> 3;           // workgroup index within cohort
    const int nwg = gridDim.x >> 3;          // workgroups per cohort
    const int tot = 3 * E;
    const int ngroups = tot >> 2;            // groups of 4 edges (E % 4 == 0)
    const int gper = E >> 2;                 // groups per graph
    const unsigned int totU = (unsigned int)tot;

    for (int g = c * 256 + (int)threadIdx.x; g < ngroups; g += nwg * 256) {
        int graph = g / gper;
        int j4 = (g - graph * gper) << 2;
        const int* edge = (graph == 0) ? up : (graph == 1) ? ut : ug;
        int base = (graph == 0) ? 0 : (graph == 1) ? NP : NP + NT;
        int4 t4 = *(const int4*)(edge + E + j4);
        int4 s4 = *(const int4*)(edge + j4);
        int ts[4] = {t4.x, t4.y, t4.z, t4.w};
        int ss[4] = {s4.x, s4.y, s4.z, s4.w};
#pragma unroll
        for (int q = 0; q < 4; ++q) {
            int t = ts[q] + base;
            unsigned int og = (unsigned int)offs[t];
            int b = (int)(((unsigned long long)og * 8u) / totU);
            if (b == p) {
                int pos = atomicAdd(&cur[t], 1);
                ei[pos] = ss[q] + base;
            }
        }
    }
}

// ---- conv layer 1: x1[n] = dinv[n] * sum_in emb[s]*dinv[s]  (bf16 rows) ----
__global__ void conv_csr1(const int* __restrict__ offs, const int* __restrict__ ei,
                          const float* __restrict__ dinv,
                          const ushort4* __restrict__ xin, ushort4* __restrict__ xout, int N) {
    int gid = blockIdx.x * blockDim.x + threadIdx.x;
    int n = gid >> 4, l = gid & 15;
    if (n >= N) return;
    int beg = offs[n], end = offs[n + 1];
    float4 acc = {0.f, 0.f, 0.f, 0.f};
    int k = beg;
    for (; k + 3 < end; k += 4) {
        int s0 = ei[k], s1 = ei[k + 1], s2 = ei[k + 2], s3 = ei[k + 3];
        float w0 = dinv[s0], w1 = dinv[s1], w2 = dinv[s2], w3 = dinv[s3];
        ushort4 u0 = xin[(size_t)s0 * 16 + l];
        ushort4 u1 = xin[(size_t)s1 * 16 + l];
        ushort4 u2 = xin[(size_t)s2 * 16 + l];
        ushort4 u3 = xin[(size_t)s3 * 16 + l];
        acc = fma4(u2f4(u0), w0, acc);
        acc = fma4(u2f4(u1), w1, acc);
        acc = fma4(u2f4(u2), w2, acc);
        acc = fma4(u2f4(u3), w3, acc);
    }
    for (; k < end; ++k) {
        int s = ei[k];
        acc = fma4(u2f4(xin[(size_t)s * 16 + l]), dinv[s], acc);
    }
    float sc = dinv[n];
    float4 r; r.x = acc.x * sc; r.y = acc.y * sc; r.z = acc.z * sc; r.w = acc.w * sc;
    xout[(size_t)n * 16 + l] = f2u4(r);
}

// ---- conv layer 2 + epilogue: out[n] = (emb + x1 + dinv[n]*sum x1[s]*dinv[s]) / 3 ----
__global__ void conv_csr2(const int* __restrict__ offs, const int* __restrict__ ei,
                          const float* __restrict__ dinv,
                          const ushort4* __restrict__ emb, const ushort4* __restrict__ x1,
                          ushort4* __restrict__ out, int N) {
    int gid = blockIdx.x * blockDim.x + threadIdx.x;
    int n = gid >> 4, l = gid & 15;
    if (n >= N) return;
    int beg = offs[n], end = offs[n + 1];
    float4 acc = {0.f, 0.f, 0.f, 0.f};
    int k = beg;
    for (; k + 3 < end; k += 4) {
        int s0 = ei[k], s1 = ei[k + 1], s2 = ei[k + 2], s3 = ei[k + 3];
        float w0 = dinv[s0], w1 = dinv[s1], w2 = dinv[s2], w3 = dinv[s3];
        ushort4 u0 = x1[(size_t)s0 * 16 + l];
        ushort4 u1 = x1[(size_t)s1 * 16 + l];
        ushort4 u2 = x1[(size_t)s2 * 16 + l];
        ushort4 u3 = x1[(size_t)s3 * 16 + l];
        acc = fma4(u2f4(u0), w0, acc);
        acc = fma4(u2f4(u1), w1, acc);
        acc = fma4(u2f4(u2), w2, acc);
        acc = fma4(u2f4(u3), w3, acc);
    }
    for (; k < end; ++k) {
        int s = ei[k];
        acc = fma4(u2f4(x1[(size_t)s * 16 + l]), dinv[s], acc);
    }
    float sc = dinv[n];
    size_t idx = (size_t)n * 16 + l;
    float4 em = u2f4(emb[idx]), x = u2f4(x1[idx]);
    const float third = 1.0f / 3.0f;
    float4 o;
    o.x = (em.x + x.x + acc.x * sc) * third;
    o.y = (em.y + x.y + acc.y * sc) * third;
    o.z = (em.z + x.z + acc.z * sc) * third;
    o.w = (em.w + x.w + acc.w * sc) * third;
    out[idx] = f2u4(o);
}

// ---- final: 4 edges per 16-lane group; bf16 node rows ----
__global__ void final_kernel(const int* __restrict__ up_e, const int* __restrict__ ut_e,
                             const int* __restrict__ utag_e,
                             const float* __restrict__ src_feat, const float* __restrict__ dst_feat,
                             const ushort4* __restrict__ O,
                             const float4* __restrict__ W_s4, const float4* __restrict__ b_s4,
                             const float4* __restrict__ W_d4, const float4* __restrict__ b_d4,
                             float* __restrict__ out, int E, int NP, int NT) {
    int gid = blockIdx.x * blockDim.x + threadIdx.x;
    int grp = gid >> 4;
    int l = gid & 15;
    int e0 = grp * 4;
    if (e0 >= E) return;
    int lane = threadIdx.x & 63;
    int gbase = lane & 48;

    ushort4 as[4][3], bs[4][3];
    float fsc[4], fdc[4];
#pragma unroll
    for (int j = 0; j < 4; ++j) {
        int e = e0 + j; if (e > E - 1) e = E - 1;
        int sp = up_e[e],             dp = up_e[E + e];
        int st = ut_e[e] + NP,        dt = ut_e[E + e] + NP;
        int sg = utag_e[e] + NP + NT, dg = utag_e[E + e] + NP + NT;
        as[j][0] = O[(size_t)sp * 16 + l];
        as[j][1] = O[(size_t)st * 16 + l];
        as[j][2] = O[(size_t)sg * 16 + l];
        bs[j][0] = O[(size_t)dp * 16 + l];
        bs[j][1] = O[(size_t)dt * 16 + l];
        bs[j][2] = O[(size_t)dg * 16 + l];
        fsc[j] = src_feat[(size_t)e * 16 + l];
        fdc[j] = dst_feat[(size_t)e * 16 + l];
    }

    float4 fs[4], fd[4];
    float4 bsv = b_s4[l], bdv = b_d4[l];
#pragma unroll
    for (int j = 0; j < 4; ++j) { fs[j] = bsv; fd[j] = bdv; }

#pragma unroll
    for (int k = 0; k < 16; ++k) {
        float4 ws = W_s4[k * 16 + l];
        float4 wd = W_d4[k * 16 + l];
#pragma unroll
        for (int j = 0; j < 4; ++j) {
            float a = __shfl(fsc[j], gbase + k, 64);
            float c = __shfl(fdc[j], gbase + k, 64);
            fs[j] = fma4(ws, a, fs[j]);
            fd[j] = fma4(wd, c, fd[j]);
        }
    }

    const float third = 1.0f / 3.0f;
    float prod[4];
#pragma unroll
    for (int j = 0; j < 4; ++j) {
        float4 vp = u2f4(as[j][0]), vt = u2f4(as[j][1]), vg = u2f4(as[j][2]);
        float4 P, Q;
        P.x = (vp.x + vt.x + vg.x) * third + fs[j].x;
        P.y = (vp.y + vt.y + vg.y) * third + fs[j].y;
        P.z = (vp.z + vt.z + vg.z) * third + fs[j].z;
        P.w = (vp.w + vt.w + vg.w) * third + fs[j].w;
        vp = u2f4(bs[j][0]); vt = u2f4(bs[j][1]); vg = u2f4(bs[j][2]);
        Q.x = (vp.x + vt.x + vg.x) * third + fd[j].x;
        Q.y = (vp.y + vt.y + vg.y) * third + fd[j].y;
        Q.z = (vp.z + vt.z + vg.z) * third + fd[j].z;
        Q.w = (vp.w + vt.w + vg.w) * third + fd[j].w;
        float p = P.x * Q.x + P.y * Q.y + P.z * Q.z + P.w * Q.w;
        p += __shfl_xor(p, 8, 64);
        p += __shfl_xor(p, 4, 64);
        p += __shfl_xor(p, 2, 64);
        p += __shfl_xor(p, 1, 64);
        prod[j] = p;
    }
    if (l == 0) {
#pragma unroll
        for (int j = 0; j < 4; ++j)
            if (e0 + j < E) out[e0 + j] = prod[j];
    }
}

extern "C" void kernel_launch(void* const* d_in, const int* in_sizes, int n_in,
                              void* d_out, int out_size, void* d_ws, size_t ws_size,
                              hipStream_t stream) {
    const int*   up_e     = (const int*)d_in[0];
    const int*   ut_e     = (const int*)d_in[1];
    const int*   utag_e   = (const int*)d_in[2];
    const float* src_feat = (const float*)d_in[3];
    const float* dst_feat = (const float*)d_in[4];
    const float* up_emb   = (const float*)d_in[5];
    const float* ut_emb   = (const float*)d_in[6];
    const float* utag_emb = (const float*)d_in[7];
    const float* W_src    = (const float*)d_in[8];
    const float* b_src    = (const float*)d_in[9];
    const float* W_dst    = (const float*)d_in[10];
    const float* b_dst    = (const float*)d_in[11];
    float* out = (float*)d_out;

    const int E  = in_sizes[0] / 2;
    const int NP = in_sizes[5] / DIM;
    const int NT = in_sizes[6] / DIM;
    const int NG = in_sizes[7] / DIM;
    const int NTOT = NP + NT + NG;
    const int NB = (NTOT + 255) / 256;          // scan blocks

    // ---- workspace layout ----
    char* w = (char*)d_ws;
    int*  degi = (int*)w;                       w += (size_t)NTOT * 4;
    int*  offs = (int*)w;                       w += (size_t)(NTOT + 1) * 4;
    int*  cur  = (int*)w;                       w += (size_t)NTOT * 4;
    int*  bsum = (int*)w;                       w += (size_t)1024 * 4;
    float* dinv = (float*)w;                    w += (size_t)NTOT * 4;
    w = (char*)(((uintptr_t)w + 127) & ~(uintptr_t)127);
    int*  ei   = (int*)w;                       w += (size_t)3 * E * 4;
    w = (char*)(((uintptr_t)w + 127) & ~(uintptr_t)127);
    ushort4* embh = (ushort4*)w;                w += (size_t)NTOT * 16 * 8;   // bf16 emb
    ushort4* x1h  = (ushort4*)w;                w += (size_t)NTOT * 16 * 8;   // bf16 x1
    ushort4* outh = (ushort4*)w;                // bf16 aggregated node table

    const int BT = 256;

    hipMemsetAsync(degi, 0, (size_t)NTOT * 4, stream);

    // fused degree count + emb bf16 convert
    {
        long long tot = 3LL * E + (long long)NTOT * 16;
        deg_cvt_kernel<<<dim3((tot + BT - 1) / BT), dim3(BT), 0, stream>>>(
            up_e + E, ut_e + E, utag_e + E, degi,
            (const float4*)up_emb, (const float4*)ut_emb, (const float4*)utag_emb,
            embh, NP, NT, NG, E);
    }

    // global parallel exclusive scan over all nodes (+ dinv)
    block_sums<<<dim3(NB), dim3(BT), 0, stream>>>(degi, bsum, NTOT);
    scan_bsums<<<dim3(1), dim3(1024), 0, stream>>>(bsum, NB);
    scatter_offs<<<dim3(NB), dim3(BT), 0, stream>>>(degi, bsum, offs, cur, dinv, NTOT, 3 * E);

    // XCD-partitioned CSR build: 1024 wgs = 8 cohorts x 128
    permute_part<<<dim3(1024), dim3(BT), 0, stream>>>(
        up_e, ut_e, utag_e, offs, cur, ei, NP, NT, E);

    // conv layers over ALL nodes
    int nb = ((size_t)NTOT * 16 + BT - 1) / BT;
    conv_csr1<<<dim3(nb), dim3(BT), 0, stream>>>(offs, ei, dinv, embh, x1h, NTOT);
    conv_csr2<<<dim3(nb), dim3(BT), 0, stream>>>(offs, ei, dinv, embh, x1h, outh, NTOT);

    // final: 4 edges per 16-lane group
    long long groups = (E + 3) / 4;
    final_kernel<<<dim3((groups * 16 + BT - 1) / BT), dim3(BT), 0, stream>>>(
        up_e, ut_e, utag_e, src_feat, dst_feat, outh,
        (const float4*)W_src, (const float4*)b_src,
        (const float4*)W_dst, (const float4*)b_dst, out, E, NP, NT);
}